// Round 1
// 640.589 us; speedup vs baseline: 1.1418x; 1.1418x over previous
//
#include <hip/hip_runtime.h>
#include <cmath>

// SparseCausalAttentionBlock on MI355X (gfx950).
// Round 6: all GEMMs moved from the 128x128 2-barrier structure (R5: 470 TF,
// MfmaUtil 20%, 8.4M LDS bank conflicts) to the 256x256 8-phase template:
//  - BM=BN=256, BK=64, 512 thr = 8 waves (2M x 4N), per-wave C = 128x64
//  - 128 KiB LDS, double-buffered; staging via global_load_lds width=16 with
//    PRE-SWIZZLED global source (LDS dest must stay linear), reads XOR-swizzled
//    col ^= (row&7)<<4  -> conflict-free ds_read_b128
//  - 4 phases per K-tile: {ds_read subtile | stage 1 half-tile | s_barrier |
//    setprio(1) 16 MFMA setprio(0) | s_barrier}; raw s_barrier (no vmcnt drain)
//  - counted s_waitcnt vmcnt(4) once per K-tile (2 half-tiles stay in flight)
//  - bijective XCD-chunked block swizzle
// Stage/read safety: A-halves of tile kt fully read by end P2, B-halves by P3;
// kt+1.B0/B1 staged P1/P2 (other buffer), kt+2.A0/A1 staged P3/P4 (cur buffer).
// Epilogue identical to R5 (per-wave LDS staging, full-line loads/stores).
// Attention / LN / conv kernels unchanged from R5.

typedef unsigned short u16;
typedef unsigned int u32;
typedef __bf16 bf16_t;
typedef bf16_t bf16x8 __attribute__((ext_vector_type(8)));
typedef float f32x4 __attribute__((ext_vector_type(4)));

#define DEV __device__ __forceinline__
#define MFMA16(a, b, c) __builtin_amdgcn_mfma_f32_16x16x32_bf16(a, b, c, 0, 0, 0)

DEV u16 f2b(float f) {  // fp32 -> bf16 RNE
  u32 u = __float_as_uint(f);
  u32 r = u + 0x7fffu + ((u >> 16) & 1u);
  return (u16)(r >> 16);
}
DEV float b2f(u16 b) { return __uint_as_float(((u32)b) << 16); }

DEV void g2l16(const void* g, void* l) {
  // async global->LDS, 16B/lane; LDS dest = wave-uniform base + lane*16
  __builtin_amdgcn_global_load_lds((const __attribute__((address_space(1))) void*)g,
                                   (__attribute__((address_space(3))) void*)l,
                                   16, 0, 0);
}

// ---------------- fp32 -> bf16 converter (2048 elems / block) ---------------
__global__ __launch_bounds__(256) void conv1(const float* __restrict__ s,
                                             u16* __restrict__ d) {
  size_t idx = ((size_t)blockIdx.x * 256 + threadIdx.x) * 8;
  float4 a = *(const float4*)(s + idx);
  float4 b = *(const float4*)(s + idx + 4);
  float v[8] = {a.x, a.y, a.z, a.w, b.x, b.y, b.z, b.w};
  union { u16 q[8]; uint4 u; } pk;
#pragma unroll
  for (int i = 0; i < 8; ++i) pk.q[i] = f2b(v[i]);
  *(uint4*)(d + idx) = pk.u;
}

// ---------------- bf16 MFMA GEMM 256x256x64, 8-phase: C = A @ B^T -----------
template <bool GELU, bool RES32, bool RESB, bool OUT32, bool OUTB>
__global__ __launch_bounds__(512, 2) void gemm256(
    const u16* __restrict__ A, const u16* __restrict__ B,
    const float* __restrict__ bias, const float* __restrict__ res32,
    const u16* __restrict__ resb, float* __restrict__ out32,
    u16* __restrict__ outb, int M, int N, int K) {
  // LDS map: bufA(b,h) = b*32768 + h*16384 ; bufB(b,h) = 65536 + b*32768 + h*16384
  __shared__ __align__(16) char smem[131072];
  const int tid = threadIdx.x;
  const int lane = tid & 63, wv = tid >> 6;
  const int warp_m = wv >> 2, warp_n = wv & 3;
  const int lrow = lane & 15, quad = lane >> 4;

  // bijective XCD-chunked block swizzle (m204 form)
  int idx = blockIdx.x;
  {
    const int nwg = gridDim.x;
    if (nwg >= 8) {
      const int q = nwg >> 3, r = nwg & 7;
      const int xcd = idx & 7, rk = idx >> 3;
      idx = (xcd < r ? xcd * (q + 1) : r * (q + 1) + (xcd - r) * q) + rk;
    }
  }
  const int nx = N >> 8;
  const int m0 = (idx / nx) * 256, n0 = (idx % nx) * 256;

  // staging constants: linear LDS dest p = i*8192 + wv*1024 + lane*16
  //   -> row = i*64 + wv*8 + (lane>>3), pcol = (lane&7)*16
  //   logical col = pcol ^ ((row&7)<<4)  (pre-swizzled source)
  const int srow = wv * 8 + (lane >> 3);
  const int scol = (((lane & 7) ^ ((lane >> 3) & 7)) << 4);  // bytes
  const int sdst = wv * 1024 + lane * 16;
  // read constants: frag (m,kk) physical col = (kk*64 + quad*16) ^ ((lane&7)<<4)
  const int x4 = (lane & 7) << 4;
  const int col0 = (quad * 16) ^ x4;
  const int col1 = (64 + quad * 16) ^ x4;
  const int aRowB = lrow * 128;                          // + m*2048
  const int bRowB = ((warp_n & 1) * 64 + lrow) * 128;    // + n*2048

  const int nt = K >> 6;

  auto stageH = [&](const u16* __restrict__ G, int row0, int kt, int ldsOff) {
    const char* g0 = (const char*)G + (((size_t)(row0 + srow) * K + kt * 64) << 1) + scol;
    char* l0 = smem + ldsOff + sdst;
    g2l16(g0, l0);
    g2l16(g0 + ((size_t)K << 7), l0 + 8192);  // +64 rows
  };

  f32x4 acc[8][4];
  f32x4 zero4 = {0.f, 0.f, 0.f, 0.f};
#pragma unroll
  for (int a = 0; a < 8; ++a)
#pragma unroll
    for (int b = 0; b < 4; ++b) acc[a][b] = zero4;

  // prologue: tile0 fully (8 loads) + tile1 A-halves (4 loads); keep 4 in flight
  stageH(A, m0, 0, 0);
  stageH(A, m0 + 128, 0, 16384);
  stageH(B, n0, 0, 65536);
  stageH(B, n0 + 128, 0, 65536 + 16384);
  stageH(A, m0, 1, 32768);
  stageH(A, m0 + 128, 1, 32768 + 16384);
  asm volatile("s_waitcnt vmcnt(4)" ::: "memory");
  asm volatile("s_barrier" ::: "memory");

  int cur = 0;
  bf16x8 afr[8][2], bfr[2][2];
  for (int kt = 0; kt < nt; ++kt) {
    const char* cA = smem + cur * 32768 + warp_m * 16384;
    const char* cB = smem + 65536 + cur * 32768 + (warp_n >> 1) * 16384;
    const int nb = cur ^ 1;
    const int kt1 = (kt + 1 < nt) ? kt + 1 : nt - 1;
    const int kt2 = (kt + 2 < nt) ? kt + 2 : nt - 1;

    // ---- P1: read A m0-3 (8) + B n0-1 (4); stage kt+1.B0 -> nbuf
#pragma unroll
    for (int m = 0; m < 4; ++m) {
      afr[m][0] = *(const bf16x8*)(cA + aRowB + m * 2048 + col0);
      afr[m][1] = *(const bf16x8*)(cA + aRowB + m * 2048 + col1);
    }
#pragma unroll
    for (int n = 0; n < 2; ++n) {
      bfr[n][0] = *(const bf16x8*)(cB + bRowB + n * 2048 + col0);
      bfr[n][1] = *(const bf16x8*)(cB + bRowB + n * 2048 + col1);
    }
    stageH(B, n0, kt1, 65536 + nb * 32768);
    asm volatile("s_barrier" ::: "memory");
    __builtin_amdgcn_s_setprio(1);
#pragma unroll
    for (int m = 0; m < 4; ++m)
#pragma unroll
      for (int n = 0; n < 2; ++n) {
        acc[m][n] = MFMA16(afr[m][0], bfr[n][0], acc[m][n]);
        acc[m][n] = MFMA16(afr[m][1], bfr[n][1], acc[m][n]);
      }
    __builtin_amdgcn_s_setprio(0);
    asm volatile("s_barrier" ::: "memory");

    // ---- P2: read A m4-7 (8); stage kt+1.B1 -> nbuf
#pragma unroll
    for (int m = 4; m < 8; ++m) {
      afr[m][0] = *(const bf16x8*)(cA + aRowB + m * 2048 + col0);
      afr[m][1] = *(const bf16x8*)(cA + aRowB + m * 2048 + col1);
    }
    stageH(B, n0 + 128, kt1, 65536 + nb * 32768 + 16384);
    asm volatile("s_barrier" ::: "memory");
    __builtin_amdgcn_s_setprio(1);
#pragma unroll
    for (int m = 4; m < 8; ++m)
#pragma unroll
      for (int n = 0; n < 2; ++n) {
        acc[m][n] = MFMA16(afr[m][0], bfr[n][0], acc[m][n]);
        acc[m][n] = MFMA16(afr[m][1], bfr[n][1], acc[m][n]);
      }
    __builtin_amdgcn_s_setprio(0);
    asm volatile("s_barrier" ::: "memory");

    // ---- P3: read B n2-3 (4); stage kt+2.A0 -> cur (A reads done at P2)
#pragma unroll
    for (int n = 0; n < 2; ++n) {
      bfr[n][0] = *(const bf16x8*)(cB + bRowB + (n + 2) * 2048 + col0);
      bfr[n][1] = *(const bf16x8*)(cB + bRowB + (n + 2) * 2048 + col1);
    }
    stageH(A, m0, kt2, cur * 32768);
    asm volatile("s_barrier" ::: "memory");
    __builtin_amdgcn_s_setprio(1);
#pragma unroll
    for (int m = 0; m < 4; ++m)
#pragma unroll
      for (int n = 0; n < 2; ++n) {
        acc[m][n + 2] = MFMA16(afr[m][0], bfr[n][0], acc[m][n + 2]);
        acc[m][n + 2] = MFMA16(afr[m][1], bfr[n][1], acc[m][n + 2]);
      }
    __builtin_amdgcn_s_setprio(0);
    asm volatile("s_barrier" ::: "memory");

    // ---- P4: stage kt+2.A1 -> cur; MFMA m4-7 x n2-3; counted vmcnt
    stageH(A, m0 + 128, kt2, cur * 32768 + 16384);
    asm volatile("s_barrier" ::: "memory");
    __builtin_amdgcn_s_setprio(1);
#pragma unroll
    for (int m = 4; m < 8; ++m)
#pragma unroll
      for (int n = 0; n < 2; ++n) {
        acc[m][n + 2] = MFMA16(afr[m][0], bfr[n][0], acc[m][n + 2]);
        acc[m][n + 2] = MFMA16(afr[m][1], bfr[n][1], acc[m][n + 2]);
      }
    __builtin_amdgcn_s_setprio(0);
    asm volatile("s_waitcnt vmcnt(4)" ::: "memory");
    asm volatile("s_barrier" ::: "memory");
    cur = nb;
  }

  // drain everything (incl. clamped junk stages) before reusing LDS
  asm volatile("s_waitcnt vmcnt(0)" ::: "memory");
  __syncthreads();

  // ---- epilogue: per-wave LDS staging (16 rows x 68 floats), full-line IO
  float* cw = (float*)(smem + (size_t)wv * 4352);
  const int row16 = lane >> 2;
  const int c0 = (lane & 3) * 16;
  const int gcb = n0 + warp_n * 64 + c0;
  float bias16[16];
#pragma unroll
  for (int t = 0; t < 4; ++t) {
    float4 b4 = *(const float4*)(bias + gcb + t * 4);
    bias16[t * 4 + 0] = b4.x; bias16[t * 4 + 1] = b4.y;
    bias16[t * 4 + 2] = b4.z; bias16[t * 4 + 3] = b4.w;
  }

#pragma unroll
  for (int fm = 0; fm < 8; ++fm) {
    // scatter acc (C-layout: row=quad*4+r, col=fn*16+lrow) into LDS
#pragma unroll
    for (int fn = 0; fn < 4; ++fn)
#pragma unroll
      for (int r = 0; r < 4; ++r)
        cw[(quad * 4 + r) * 68 + fn * 16 + lrow] = acc[fm][fn][r];
    // gather back: 16 contiguous cols of one row (same-wave LDS, in-order DS)
    const int grow = m0 + warp_m * 128 + fm * 16 + row16;
    const size_t gbase = (size_t)grow * N + gcb;
    const float* crp = &cw[row16 * 68 + c0];
    float v[16];
#pragma unroll
    for (int t = 0; t < 4; ++t) {
      f32x4 q = *(const f32x4*)(crp + t * 4);
      v[t * 4 + 0] = q[0] + bias16[t * 4 + 0];
      v[t * 4 + 1] = q[1] + bias16[t * 4 + 1];
      v[t * 4 + 2] = q[2] + bias16[t * 4 + 2];
      v[t * 4 + 3] = q[3] + bias16[t * 4 + 3];
    }
    if (RES32) {
#pragma unroll
      for (int t = 0; t < 4; ++t) {
        float4 rr = *(const float4*)(res32 + gbase + t * 4);
        v[t * 4 + 0] += rr.x; v[t * 4 + 1] += rr.y;
        v[t * 4 + 2] += rr.z; v[t * 4 + 3] += rr.w;
      }
    }
    if (RESB) {
#pragma unroll
      for (int t = 0; t < 2; ++t) {
        union { u16 q[8]; uint4 u; } rb;
        rb.u = *(const uint4*)(resb + gbase + t * 8);
#pragma unroll
        for (int j = 0; j < 8; ++j) v[t * 8 + j] += b2f(rb.q[j]);
      }
    }
    if (GELU) {
#pragma unroll
      for (int e = 0; e < 16; ++e)
        v[e] = 0.5f * v[e] * (1.0f + erff(v[e] * 0.70710678118654752f));
    }
    if (OUT32) {
#pragma unroll
      for (int t = 0; t < 4; ++t) {
        float4 w4 = {v[t * 4 + 0], v[t * 4 + 1], v[t * 4 + 2], v[t * 4 + 3]};
        *(float4*)(out32 + gbase + t * 4) = w4;
      }
    }
    if (OUTB) {
#pragma unroll
      for (int t = 0; t < 2; ++t) {
        union { u16 q[8]; uint4 u; } pk;
#pragma unroll
        for (int j = 0; j < 8; ++j) pk.q[j] = f2b(v[t * 8 + j]);
        *(uint4*)(outb + gbase + t * 8) = pk.u;
      }
    }
  }
}

// ---------------- MFMA local windowed causal attention (window=64) ----------
__global__ __launch_bounds__(256) void local_attn_mfma(const u16* __restrict__ qkv,
                                                       u16* __restrict__ outb) {
  __shared__ u16 vt[64][152];      // V^T: [dim][key 0..143, pad->152]
  __shared__ u16 pb[4][16][104];   // per-wave P: [query][key 0..95 pad 104]
  const int tid = threadIdx.x;
  const int lane = tid & 63, w = tid >> 6;
  const int c = lane & 15, quad = lane >> 4;
  const int bx = blockIdx.x;
  const int qb = bx & 7, h = (bx >> 3) & 7, bb = bx >> 6;
  const int i0 = qb * 64;
  const int hc = h * 64;
  const size_t rbase = (size_t)bb * 512;

  {
    int r = tid >> 1;              // 0..127
    int d0 = (tid & 1) * 32;
    int key = i0 - 64 + r;
    if (key < 0) key = 0;
    if (key > 511) key = 511;
    const u16* Vr = qkv + (rbase + key) * 1536 + 1024 + hc + d0;
#pragma unroll
    for (int g = 0; g < 4; ++g) {
      union { u16 q[8]; uint4 u; } vv;
      vv.u = *(const uint4*)(Vr + g * 8);
#pragma unroll
      for (int j = 0; j < 8; ++j) vt[d0 + g * 8 + j][r] = vv.q[j];
    }
    if (tid < 128) {               // keys 128..143
      int r2 = 128 + (tid >> 3);
      int d2 = (tid & 7) * 8;
      int key2 = i0 - 64 + r2;
      if (key2 < 0) key2 = 0;
      if (key2 > 511) key2 = 511;
      const u16* Vr2 = qkv + (rbase + key2) * 1536 + 1024 + hc + d2;
      union { u16 q[8]; uint4 u; } vv2;
      vv2.u = *(const uint4*)Vr2;
#pragma unroll
      for (int j = 0; j < 8; ++j) vt[d2 + j][r2] = vv2.q[j];
    }
  }
  __syncthreads();

  const int i0w = i0 + 16 * w;
  const int kg0 = i0w - 64;

  bf16x8 qf0, qf1;
  {
    const u16* Qr = qkv + (rbase + i0w + c) * 1536 + hc + quad * 8;
    qf0 = *(const bf16x8*)Qr;
    qf1 = *(const bf16x8*)(Qr + 32);
  }

  f32x4 s[5];
#pragma unroll
  for (int kb = 0; kb < 5; ++kb) {
    int key = kg0 + kb * 16 + c; if (key < 0) key = 0;
    const u16* Kr = qkv + (rbase + key) * 1536 + 512 + hc + quad * 8;
    bf16x8 k0 = *(const bf16x8*)Kr;
    bf16x8 k1 = *(const bf16x8*)(Kr + 32);
    f32x4 z = {0.f, 0.f, 0.f, 0.f};
    z = __builtin_amdgcn_mfma_f32_16x16x32_bf16(qf0, k0, z, 0, 0, 0);
    s[kb] = __builtin_amdgcn_mfma_f32_16x16x32_bf16(qf1, k1, z, 0, 0, 0);
  }

  float mx[4];
#pragma unroll
  for (int r = 0; r < 4; ++r) {
    int row = quad * 4 + r;
    float m = -1e30f;
#pragma unroll
    for (int kb = 0; kb < 5; ++kb) {
      float v = s[kb][r] * 0.125f;
      int key = kg0 + kb * 16 + c;
      bool ok = key >= 0;
      if (kb == 0) ok = ok && (c >= row);
      if (kb == 4) ok = ok && (c <= row);
      v = ok ? v : -1e30f;
      s[kb][r] = v;
      m = fmaxf(m, v);
    }
    mx[r] = m;
  }
#pragma unroll
  for (int o = 1; o <= 8; o <<= 1)
#pragma unroll
    for (int r = 0; r < 4; ++r) mx[r] = fmaxf(mx[r], __shfl_xor(mx[r], o));

  float l[4] = {0.f, 0.f, 0.f, 0.f};
#pragma unroll
  for (int kb = 0; kb < 5; ++kb)
#pragma unroll
    for (int r = 0; r < 4; ++r) {
      u16 pq = f2b(__expf(s[kb][r] - mx[r]));
      l[r] += b2f(pq);
      pb[w][quad * 4 + r][kb * 16 + c] = pq;
    }
#pragma unroll
  for (int r = 0; r < 4; ++r) pb[w][quad * 4 + r][80 + c] = 0;
#pragma unroll
  for (int o = 1; o <= 8; o <<= 1)
#pragma unroll
    for (int r = 0; r < 4; ++r) l[r] += __shfl_xor(l[r], o);
  float inv[4];
#pragma unroll
  for (int r = 0; r < 4; ++r) inv[r] = 1.f / l[r];

  f32x4 o4[4];
#pragma unroll
  for (int nb = 0; nb < 4; ++nb) o4[nb] = f32x4{0.f, 0.f, 0.f, 0.f};
#pragma unroll
  for (int kt = 0; kt < 3; ++kt) {
    bf16x8 pa = *(const bf16x8*)&pb[w][c][kt * 32 + quad * 8];
#pragma unroll
    for (int nb = 0; nb < 4; ++nb) {
      bf16x8 vb = *(const bf16x8*)&vt[nb * 16 + c][16 * w + kt * 32 + quad * 8];
      o4[nb] = __builtin_amdgcn_mfma_f32_16x16x32_bf16(pa, vb, o4[nb], 0, 0, 0);
    }
  }
#pragma unroll
  for (int nb = 0; nb < 4; ++nb)
#pragma unroll
    for (int r = 0; r < 4; ++r) {
      int seq = i0w + quad * 4 + r;
      outb[(rbase + seq) * 512 + hc + nb * 16 + c] = f2b(o4[nb][r] * inv[r]);
    }
}

// ---------------- MFMA global attention over 32 anchors ---------------------
__global__ __launch_bounds__(256) void global_attn_mfma(const u16* __restrict__ qg,
                                                        const u16* __restrict__ kvg,
                                                        u16* __restrict__ outb) {
  __shared__ u16 vt[64][40];
  __shared__ u16 pb[4][16][40];
  const int tid = threadIdx.x;
  const int lane = tid & 63, w = tid >> 6;
  const int c = lane & 15, quad = lane >> 4;
  const int bx = blockIdx.x;
  const int qb = bx & 7, h = (bx >> 3) & 7, bb = bx >> 6;
  const int i0 = qb * 64;
  const int hc = h * 64;
  const size_t rbase = (size_t)bb * 512;

  {
    int r = tid >> 3;
    int d0 = (tid & 7) * 8;
    const u16* Vr = kvg + ((size_t)bb * 32 + r) * 1024 + 512 + hc + d0;
    union { u16 q[8]; uint4 u; } vv;
    vv.u = *(const uint4*)Vr;
#pragma unroll
    for (int j = 0; j < 8; ++j) vt[d0 + j][r] = vv.q[j];
  }
  __syncthreads();

  const int i0w = i0 + 16 * w;
  bf16x8 qf0, qf1;
  {
    const u16* Qr = qg + (rbase + i0w + c) * 512 + hc + quad * 8;
    qf0 = *(const bf16x8*)Qr;
    qf1 = *(const bf16x8*)(Qr + 32);
  }
  f32x4 s[2];
#pragma unroll
  for (int kb = 0; kb < 2; ++kb) {
    const u16* Kr = kvg + ((size_t)bb * 32 + kb * 16 + c) * 1024 + hc + quad * 8;
    bf16x8 k0 = *(const bf16x8*)Kr;
    bf16x8 k1 = *(const bf16x8*)(Kr + 32);
    f32x4 z = {0.f, 0.f, 0.f, 0.f};
    z = __builtin_amdgcn_mfma_f32_16x16x32_bf16(qf0, k0, z, 0, 0, 0);
    s[kb] = __builtin_amdgcn_mfma_f32_16x16x32_bf16(qf1, k1, z, 0, 0, 0);
  }
  float mx[4];
#pragma unroll
  for (int r = 0; r < 4; ++r)
    mx[r] = fmaxf(s[0][r] * 0.125f, s[1][r] * 0.125f);
#pragma unroll
  for (int o = 1; o <= 8; o <<= 1)
#pragma unroll
    for (int r = 0; r < 4; ++r) mx[r] = fmaxf(mx[r], __shfl_xor(mx[r], o));
  float l[4] = {0.f, 0.f, 0.f, 0.f};
#pragma unroll
  for (int kb = 0; kb < 2; ++kb)
#pragma unroll
    for (int r = 0; r < 4; ++r) {
      u16 pq = f2b(__expf(s[kb][r] * 0.125f - mx[r]));
      l[r] += b2f(pq);
      pb[w][quad * 4 + r][kb * 16 + c] = pq;
    }
#pragma unroll
  for (int o = 1; o <= 8; o <<= 1)
#pragma unroll
    for (int r = 0; r < 4; ++r) l[r] += __shfl_xor(l[r], o);
  float inv[4];
#pragma unroll
  for (int r = 0; r < 4; ++r) inv[r] = 1.f / l[r];

  f32x4 o4[4];
#pragma unroll
  for (int nb = 0; nb < 4; ++nb) o4[nb] = f32x4{0.f, 0.f, 0.f, 0.f};
  bf16x8 pa = *(const bf16x8*)&pb[w][c][quad * 8];
#pragma unroll
  for (int nb = 0; nb < 4; ++nb) {
    bf16x8 vb = *(const bf16x8*)&vt[nb * 16 + c][quad * 8];
    o4[nb] = __builtin_amdgcn_mfma_f32_16x16x32_bf16(pa, vb, o4[nb], 0, 0, 0);
  }
#pragma unroll
  for (int nb = 0; nb < 4; ++nb)
#pragma unroll
    for (int r = 0; r < 4; ++r) {
      int seq = i0w + quad * 4 + r;
      outb[(rbase + seq) * 512 + hc + nb * 16 + c] = f2b(o4[nb][r] * inv[r]);
    }
}

// ---------------- LayerNorm over 512 cols, one wave per row -----------------
__global__ __launch_bounds__(256) void ln_b2b(const u16* __restrict__ in,
                                              const float* __restrict__ gg,
                                              const float* __restrict__ bb,
                                              u16* __restrict__ outb) {
  const int lane = threadIdx.x & 63;
  const size_t row = (size_t)blockIdx.x * 4 + (threadIdx.x >> 6);
  union { u16 q[8]; uint4 u; } pk;
  pk.u = *(const uint4*)(in + row * 512 + lane * 8);
  float v[8];
#pragma unroll
  for (int e = 0; e < 8; ++e) v[e] = b2f(pk.q[e]);
  float sm = 0.f, sq = 0.f;
#pragma unroll
  for (int e = 0; e < 8; ++e) { sm += v[e]; sq += v[e] * v[e]; }
#pragma unroll
  for (int o = 32; o; o >>= 1) { sm += __shfl_xor(sm, o); sq += __shfl_xor(sq, o); }
  float mean = sm * (1.0f / 512.0f);
  float var = sq * (1.0f / 512.0f) - mean * mean;
  float rs = rsqrtf(var + 1e-5f);
  float4 ga = *(const float4*)(gg + lane * 8);
  float4 gb = *(const float4*)(gg + lane * 8 + 4);
  float4 ba = *(const float4*)(bb + lane * 8);
  float4 bbv = *(const float4*)(bb + lane * 8 + 4);
  float gv[8] = {ga.x, ga.y, ga.z, ga.w, gb.x, gb.y, gb.z, gb.w};
  float bv[8] = {ba.x, ba.y, ba.z, ba.w, bbv.x, bbv.y, bbv.z, bbv.w};
  union { u16 q[8]; uint4 u; } po;
#pragma unroll
  for (int e = 0; e < 8; ++e) po.q[e] = f2b((v[e] - mean) * rs * gv[e] + bv[e]);
  *(uint4*)(outb + row * 512 + lane * 8) = po.u;
}

__global__ __launch_bounds__(256) void ln_f2f(const float* __restrict__ in,
                                              const float* __restrict__ gg,
                                              const float* __restrict__ bb,
                                              float* __restrict__ out) {
  const int lane = threadIdx.x & 63;
  const size_t row = (size_t)blockIdx.x * 4 + (threadIdx.x >> 6);
  const float* p = in + row * 512 + lane * 8;
  float4 a = *(const float4*)p;
  float4 b = *(const float4*)(p + 4);
  float v[8] = {a.x, a.y, a.z, a.w, b.x, b.y, b.z, b.w};
  float sm = 0.f, sq = 0.f;
#pragma unroll
  for (int e = 0; e < 8; ++e) { sm += v[e]; sq += v[e] * v[e]; }
#pragma unroll
  for (int o = 32; o; o >>= 1) { sm += __shfl_xor(sm, o); sq += __shfl_xor(sq, o); }
  float mean = sm * (1.0f / 512.0f);
  float var = sq * (1.0f / 512.0f) - mean * mean;
  float rs = rsqrtf(var + 1e-5f);
  float4 ga = *(const float4*)(gg + lane * 8);
  float4 gb = *(const float4*)(gg + lane * 8 + 4);
  float4 ba = *(const float4*)(bb + lane * 8);
  float4 bbv = *(const float4*)(bb + lane * 8 + 4);
  float gv[8] = {ga.x, ga.y, ga.z, ga.w, gb.x, gb.y, gb.z, gb.w};
  float bv[8] = {ba.x, ba.y, ba.z, ba.w, bbv.x, bbv.y, bbv.z, bbv.w};
  float r[8];
#pragma unroll
  for (int e = 0; e < 8; ++e) r[e] = (v[e] - mean) * rs * gv[e] + bv[e];
  float4 r1 = {r[0], r[1], r[2], r[3]};
  float4 r2 = {r[4], r[5], r[6], r[7]};
  *(float4*)(out + row * 512 + lane * 8) = r1;
  *(float4*)(out + row * 512 + lane * 8 + 4) = r2;
}

// ---------------- driver -----------------------------------------------------
extern "C" void kernel_launch(void* const* d_in, const int* in_sizes, int n_in,
                              void* d_out, int out_size, void* d_ws, size_t ws_size,
                              hipStream_t stream) {
  const float* x      = (const float*)d_in[0];
  const float* anchors= (const float*)d_in[1];
  const float* lw_in  = (const float*)d_in[2];
  const float* lb_in  = (const float*)d_in[3];
  const float* lw_out = (const float*)d_in[4];
  const float* lb_out = (const float*)d_in[5];
  const float* gw_in  = (const float*)d_in[6];
  const float* gb_in  = (const float*)d_in[7];
  const float* gw_out = (const float*)d_in[8];
  const float* gb_out = (const float*)d_in[9];
  const float* w1     = (const float*)d_in[10];
  const float* b1     = (const float*)d_in[11];
  const float* w2     = (const float*)d_in[12];
  const float* b2     = (const float*)d_in[13];
  const float* g1     = (const float*)d_in[14];
  const float* be1    = (const float*)d_in[15];
  const float* g2     = (const float*)d_in[16];
  const float* be2    = (const float*)d_in[17];
  (void)in_sizes; (void)n_in; (void)out_size;
  float* out = (float*)d_out;

  char* ws = (char*)d_ws;
  size_t o = 0;
  auto nxt = [&](size_t bytes) { char* p = ws + o; o += bytes; return p; };
  u16* lwib = (u16*)nxt((size_t)1536 * 512 * 2);
  u16* lwob = (u16*)nxt((size_t)512 * 512 * 2);
  u16* gwib = (u16*)nxt((size_t)1536 * 512 * 2);
  u16* gwob = (u16*)nxt((size_t)512 * 512 * 2);
  u16* w1b  = (u16*)nxt((size_t)2048 * 512 * 2);
  u16* w2b  = (u16*)nxt((size_t)512 * 2048 * 2);
  u16* ab   = (u16*)nxt((size_t)2048 * 512 * 2);
  u16* kvgb = (u16*)nxt((size_t)2048 * 1024 * 2);
  const size_t wbytes = o;

  int nc = 1;
  while (wbytes + (size_t)(32768 / nc) * 6144 > ws_size && nc < 32) nc <<= 1;
  const int Mc = 32768 / nc;
  const int nBat = Mc / 512;
  const int mb = Mc >> 8;   // 256-row tiles
  u16* BIGb = (u16*)nxt((size_t)Mc * 4096);
  u16* Pb   = (u16*)nxt((size_t)Mc * 1024);
  u16* Qb   = (u16*)nxt((size_t)Mc * 1024);
  u16* Sb   = BIGb + (size_t)Mc * 1536;

  conv1<<<384, 256, 0, stream>>>(lw_in, lwib);
  conv1<<<128, 256, 0, stream>>>(lw_out, lwob);
  conv1<<<384, 256, 0, stream>>>(gw_in, gwib);
  conv1<<<128, 256, 0, stream>>>(gw_out, gwob);
  conv1<<<512, 256, 0, stream>>>(w1, w1b);
  conv1<<<512, 256, 0, stream>>>(w2, w2b);
  conv1<<<512, 256, 0, stream>>>(anchors, ab);
  gemm256<false, false, false, false, true><<<8 * 4, 512, 0, stream>>>(
      ab, gwib + 512 * 512, gb_in + 512, nullptr, nullptr, nullptr, kvgb, 2048, 1024, 512);

  for (int ck = 0; ck < nc; ++ck) {
    const size_t r0 = (size_t)ck * Mc;
    const float* xck = x + r0 * 512;
    conv1<<<Mc / 4, 256, 0, stream>>>(xck, Pb);
    gemm256<false, false, false, false, true><<<mb * 6, 512, 0, stream>>>(
        Pb, lwib, lb_in, nullptr, nullptr, nullptr, BIGb, Mc, 1536, 512);
    local_attn_mfma<<<nBat * 64, 256, 0, stream>>>(BIGb, Sb);
    gemm256<false, true, false, false, true><<<mb * 2, 512, 0, stream>>>(
        Sb, lwob, lb_out, xck, nullptr, nullptr, Qb, Mc, 512, 512);
    gemm256<false, false, false, false, true><<<mb * 2, 512, 0, stream>>>(
        Qb, gwib, gb_in, nullptr, nullptr, nullptr, Pb, Mc, 512, 512);
    global_attn_mfma<<<nBat * 64, 256, 0, stream>>>(Pb, kvgb + (r0 / 512) * 32 * 1024, Sb);
    gemm256<false, false, true, false, true><<<mb * 2, 512, 0, stream>>>(
        Sb, gwob, gb_out, nullptr, Qb, nullptr, Pb, Mc, 512, 512);
    ln_b2b<<<Mc / 4, 256, 0, stream>>>(Pb, g1, be1, Qb);
    gemm256<true, false, false, false, true><<<mb * 8, 512, 0, stream>>>(
        Qb, w1b, b1, nullptr, nullptr, nullptr, BIGb, Mc, 2048, 512);
    gemm256<false, false, true, true, false><<<mb * 2, 512, 0, stream>>>(
        BIGb, w2b, b2, nullptr, Qb, out + r0 * 512, nullptr, Mc, 512, 2048);
    ln_f2f<<<Mc / 4, 256, 0, stream>>>(out + r0 * 512, g2, be2, out + r0 * 512);
  }
}

// Round 2
// 612.242 us; speedup vs baseline: 1.1947x; 1.0463x over previous
//
#include <hip/hip_runtime.h>
#include <cmath>

// SparseCausalAttentionBlock on MI355X (gfx950).
// Round 7: schedule pinning + cheap GELU.
// R6 profile: FFN1 123us, MfmaUtil 23% (vs m201 template's 62%), VALUBusy 42%,
// bank conflicts 0 (swizzle verified). Theory: (a) inline-asm s_barrier with
// "memory" clobber does NOT pin register-only MFMAs (rule 18) -> compiler
// glued MFMA to ds_reads, destroying phase overlap; (b) 128 erff/thread in the
// GELU epilogue ~15-20us of pure VALU. Fixes: sched_barrier(0) at all phase
// region boundaries + explicit post-barrier lgkmcnt(0) (+lgkmcnt(8) cap in
// P1), and A&S 7.1.26 erf (rcp+exp+12 FMA, err 1.5e-7) instead of erff.
// Everything else (tiles, swizzle, vmcnt(4), epilogue layout) unchanged.

typedef unsigned short u16;
typedef unsigned int u32;
typedef __bf16 bf16_t;
typedef bf16_t bf16x8 __attribute__((ext_vector_type(8)));
typedef float f32x4 __attribute__((ext_vector_type(4)));

#define DEV __device__ __forceinline__
#define MFMA16(a, b, c) __builtin_amdgcn_mfma_f32_16x16x32_bf16(a, b, c, 0, 0, 0)
#define SBAR() __builtin_amdgcn_sched_barrier(0)

DEV u16 f2b(float f) {  // fp32 -> bf16 RNE
  u32 u = __float_as_uint(f);
  u32 r = u + 0x7fffu + ((u >> 16) & 1u);
  return (u16)(r >> 16);
}
DEV float b2f(u16 b) { return __uint_as_float(((u32)b) << 16); }

DEV float gelu_erf(float x) {
  // gelu(x) = 0.5 x (1 + erf(x/sqrt2)); erf via A&S 7.1.26 (max err 1.5e-7)
  float y = x * 0.70710678118654752f;
  float ay = fabsf(y);
  float t = __builtin_amdgcn_rcpf(1.0f + 0.3275911f * ay);
  float p = t * (0.254829592f +
            t * (-0.284496736f +
            t * (1.421413741f +
            t * (-1.453152027f + t * 1.061405429f))));
  float e = 1.0f - p * __expf(-y * y);
  float erfv = (y < 0.f) ? -e : e;
  return 0.5f * x * (1.0f + erfv);
}

DEV void g2l16(const void* g, void* l) {
  // async global->LDS, 16B/lane; LDS dest = wave-uniform base + lane*16
  __builtin_amdgcn_global_load_lds((const __attribute__((address_space(1))) void*)g,
                                   (__attribute__((address_space(3))) void*)l,
                                   16, 0, 0);
}

// ---------------- fp32 -> bf16 converter (2048 elems / block) ---------------
__global__ __launch_bounds__(256) void conv1(const float* __restrict__ s,
                                             u16* __restrict__ d) {
  size_t idx = ((size_t)blockIdx.x * 256 + threadIdx.x) * 8;
  float4 a = *(const float4*)(s + idx);
  float4 b = *(const float4*)(s + idx + 4);
  float v[8] = {a.x, a.y, a.z, a.w, b.x, b.y, b.z, b.w};
  union { u16 q[8]; uint4 u; } pk;
#pragma unroll
  for (int i = 0; i < 8; ++i) pk.q[i] = f2b(v[i]);
  *(uint4*)(d + idx) = pk.u;
}

// ---------------- bf16 MFMA GEMM 256x256x64, 8-phase: C = A @ B^T -----------
template <bool GELU, bool RES32, bool RESB, bool OUT32, bool OUTB>
__global__ __launch_bounds__(512, 2) void gemm256(
    const u16* __restrict__ A, const u16* __restrict__ B,
    const float* __restrict__ bias, const float* __restrict__ res32,
    const u16* __restrict__ resb, float* __restrict__ out32,
    u16* __restrict__ outb, int M, int N, int K) {
  // LDS map: bufA(b,h) = b*32768 + h*16384 ; bufB(b,h) = 65536 + b*32768 + h*16384
  __shared__ __align__(16) char smem[131072];
  const int tid = threadIdx.x;
  const int lane = tid & 63, wv = tid >> 6;
  const int warp_m = wv >> 2, warp_n = wv & 3;
  const int lrow = lane & 15, quad = lane >> 4;

  // bijective XCD-chunked block swizzle (m204 form)
  int idx = blockIdx.x;
  {
    const int nwg = gridDim.x;
    if (nwg >= 8) {
      const int q = nwg >> 3, r = nwg & 7;
      const int xcd = idx & 7, rk = idx >> 3;
      idx = (xcd < r ? xcd * (q + 1) : r * (q + 1) + (xcd - r) * q) + rk;
    }
  }
  const int nx = N >> 8;
  const int m0 = (idx / nx) * 256, n0 = (idx % nx) * 256;

  // staging constants: linear LDS dest p = i*8192 + wv*1024 + lane*16
  //   -> row = i*64 + wv*8 + (lane>>3), pcol = (lane&7)*16
  //   logical col = pcol ^ ((row&7)<<4)  (pre-swizzled source)
  const int srow = wv * 8 + (lane >> 3);
  const int scol = (((lane & 7) ^ ((lane >> 3) & 7)) << 4);  // bytes
  const int sdst = wv * 1024 + lane * 16;
  // read constants: frag (m,kk) physical col = (kk*64 + quad*16) ^ ((lane&7)<<4)
  const int x4 = (lane & 7) << 4;
  const int col0 = (quad * 16) ^ x4;
  const int col1 = (64 + quad * 16) ^ x4;
  const int aRowB = lrow * 128;                          // + m*2048
  const int bRowB = ((warp_n & 1) * 64 + lrow) * 128;    // + n*2048

  const int nt = K >> 6;

  auto stageH = [&](const u16* __restrict__ G, int row0, int kt, int ldsOff) {
    const char* g0 = (const char*)G + (((size_t)(row0 + srow) * K + kt * 64) << 1) + scol;
    char* l0 = smem + ldsOff + sdst;
    g2l16(g0, l0);
    g2l16(g0 + ((size_t)K << 7), l0 + 8192);  // +64 rows
  };

  f32x4 acc[8][4];
  f32x4 zero4 = {0.f, 0.f, 0.f, 0.f};
#pragma unroll
  for (int a = 0; a < 8; ++a)
#pragma unroll
    for (int b = 0; b < 4; ++b) acc[a][b] = zero4;

  // prologue: tile0 fully (8 loads) + tile1 A-halves (4 loads); keep 4 in flight
  stageH(A, m0, 0, 0);
  stageH(A, m0 + 128, 0, 16384);
  stageH(B, n0, 0, 65536);
  stageH(B, n0 + 128, 0, 65536 + 16384);
  stageH(A, m0, 1, 32768);
  stageH(A, m0 + 128, 1, 32768 + 16384);
  SBAR();
  asm volatile("s_waitcnt vmcnt(4)" ::: "memory");
  asm volatile("s_barrier" ::: "memory");
  SBAR();

  int cur = 0;
  bf16x8 afr[8][2], bfr[2][2];
  for (int kt = 0; kt < nt; ++kt) {
    const char* cA = smem + cur * 32768 + warp_m * 16384;
    const char* cB = smem + 65536 + cur * 32768 + (warp_n >> 1) * 16384;
    const int nb = cur ^ 1;
    const int kt1 = (kt + 1 < nt) ? kt + 1 : nt - 1;
    const int kt2 = (kt + 2 < nt) ? kt + 2 : nt - 1;

    // ---- P1: read A m0-3 (8) + B n0-1 (4); stage kt+1.B0 -> nbuf
#pragma unroll
    for (int m = 0; m < 4; ++m) {
      afr[m][0] = *(const bf16x8*)(cA + aRowB + m * 2048 + col0);
      afr[m][1] = *(const bf16x8*)(cA + aRowB + m * 2048 + col1);
    }
#pragma unroll
    for (int n = 0; n < 2; ++n) {
      bfr[n][0] = *(const bf16x8*)(cB + bRowB + n * 2048 + col0);
      bfr[n][1] = *(const bf16x8*)(cB + bRowB + n * 2048 + col1);
    }
    stageH(B, n0, kt1, 65536 + nb * 32768);
    SBAR();
    asm volatile("s_waitcnt lgkmcnt(8)" ::: "memory");
    asm volatile("s_barrier" ::: "memory");
    asm volatile("s_waitcnt lgkmcnt(0)" ::: "memory");
    SBAR();
    __builtin_amdgcn_s_setprio(1);
#pragma unroll
    for (int m = 0; m < 4; ++m)
#pragma unroll
      for (int n = 0; n < 2; ++n) {
        acc[m][n] = MFMA16(afr[m][0], bfr[n][0], acc[m][n]);
        acc[m][n] = MFMA16(afr[m][1], bfr[n][1], acc[m][n]);
      }
    __builtin_amdgcn_s_setprio(0);
    SBAR();
    asm volatile("s_barrier" ::: "memory");
    SBAR();

    // ---- P2: read A m4-7 (8); stage kt+1.B1 -> nbuf
#pragma unroll
    for (int m = 4; m < 8; ++m) {
      afr[m][0] = *(const bf16x8*)(cA + aRowB + m * 2048 + col0);
      afr[m][1] = *(const bf16x8*)(cA + aRowB + m * 2048 + col1);
    }
    stageH(B, n0 + 128, kt1, 65536 + nb * 32768 + 16384);
    SBAR();
    asm volatile("s_barrier" ::: "memory");
    asm volatile("s_waitcnt lgkmcnt(0)" ::: "memory");
    SBAR();
    __builtin_amdgcn_s_setprio(1);
#pragma unroll
    for (int m = 4; m < 8; ++m)
#pragma unroll
      for (int n = 0; n < 2; ++n) {
        acc[m][n] = MFMA16(afr[m][0], bfr[n][0], acc[m][n]);
        acc[m][n] = MFMA16(afr[m][1], bfr[n][1], acc[m][n]);
      }
    __builtin_amdgcn_s_setprio(0);
    SBAR();
    asm volatile("s_barrier" ::: "memory");
    SBAR();

    // ---- P3: read B n2-3 (4); stage kt+2.A0 -> cur (A reads done at P2)
#pragma unroll
    for (int n = 0; n < 2; ++n) {
      bfr[n][0] = *(const bf16x8*)(cB + bRowB + (n + 2) * 2048 + col0);
      bfr[n][1] = *(const bf16x8*)(cB + bRowB + (n + 2) * 2048 + col1);
    }
    stageH(A, m0, kt2, cur * 32768);
    SBAR();
    asm volatile("s_barrier" ::: "memory");
    asm volatile("s_waitcnt lgkmcnt(0)" ::: "memory");
    SBAR();
    __builtin_amdgcn_s_setprio(1);
#pragma unroll
    for (int m = 0; m < 4; ++m)
#pragma unroll
      for (int n = 0; n < 2; ++n) {
        acc[m][n + 2] = MFMA16(afr[m][0], bfr[n][0], acc[m][n + 2]);
        acc[m][n + 2] = MFMA16(afr[m][1], bfr[n][1], acc[m][n + 2]);
      }
    __builtin_amdgcn_s_setprio(0);
    SBAR();
    asm volatile("s_barrier" ::: "memory");
    SBAR();

    // ---- P4: stage kt+2.A1 -> cur; MFMA m4-7 x n2-3; counted vmcnt
    stageH(A, m0 + 128, kt2, cur * 32768 + 16384);
    SBAR();
    asm volatile("s_barrier" ::: "memory");
    SBAR();
    __builtin_amdgcn_s_setprio(1);
#pragma unroll
    for (int m = 4; m < 8; ++m)
#pragma unroll
      for (int n = 0; n < 2; ++n) {
        acc[m][n + 2] = MFMA16(afr[m][0], bfr[n][0], acc[m][n + 2]);
        acc[m][n + 2] = MFMA16(afr[m][1], bfr[n][1], acc[m][n + 2]);
      }
    __builtin_amdgcn_s_setprio(0);
    SBAR();
    asm volatile("s_waitcnt vmcnt(4)" ::: "memory");
    asm volatile("s_barrier" ::: "memory");
    SBAR();
    cur = nb;
  }

  // drain everything (incl. clamped junk stages) before reusing LDS
  asm volatile("s_waitcnt vmcnt(0)" ::: "memory");
  __syncthreads();

  // ---- epilogue: per-wave LDS staging (16 rows x 68 floats), full-line IO
  float* cw = (float*)(smem + (size_t)wv * 4352);
  const int row16 = lane >> 2;
  const int c0 = (lane & 3) * 16;
  const int gcb = n0 + warp_n * 64 + c0;
  float bias16[16];
#pragma unroll
  for (int t = 0; t < 4; ++t) {
    float4 b4 = *(const float4*)(bias + gcb + t * 4);
    bias16[t * 4 + 0] = b4.x; bias16[t * 4 + 1] = b4.y;
    bias16[t * 4 + 2] = b4.z; bias16[t * 4 + 3] = b4.w;
  }

#pragma unroll
  for (int fm = 0; fm < 8; ++fm) {
    // scatter acc (C-layout: row=quad*4+r, col=fn*16+lrow) into LDS
#pragma unroll
    for (int fn = 0; fn < 4; ++fn)
#pragma unroll
      for (int r = 0; r < 4; ++r)
        cw[(quad * 4 + r) * 68 + fn * 16 + lrow] = acc[fm][fn][r];
    // gather back: 16 contiguous cols of one row (same-wave LDS, in-order DS)
    const int grow = m0 + warp_m * 128 + fm * 16 + row16;
    const size_t gbase = (size_t)grow * N + gcb;
    const float* crp = &cw[row16 * 68 + c0];
    float v[16];
#pragma unroll
    for (int t = 0; t < 4; ++t) {
      f32x4 q = *(const f32x4*)(crp + t * 4);
      v[t * 4 + 0] = q[0] + bias16[t * 4 + 0];
      v[t * 4 + 1] = q[1] + bias16[t * 4 + 1];
      v[t * 4 + 2] = q[2] + bias16[t * 4 + 2];
      v[t * 4 + 3] = q[3] + bias16[t * 4 + 3];
    }
    if (RES32) {
#pragma unroll
      for (int t = 0; t < 4; ++t) {
        float4 rr = *(const float4*)(res32 + gbase + t * 4);
        v[t * 4 + 0] += rr.x; v[t * 4 + 1] += rr.y;
        v[t * 4 + 2] += rr.z; v[t * 4 + 3] += rr.w;
      }
    }
    if (RESB) {
#pragma unroll
      for (int t = 0; t < 2; ++t) {
        union { u16 q[8]; uint4 u; } rb;
        rb.u = *(const uint4*)(resb + gbase + t * 8);
#pragma unroll
        for (int j = 0; j < 8; ++j) v[t * 8 + j] += b2f(rb.q[j]);
      }
    }
    if (GELU) {
#pragma unroll
      for (int e = 0; e < 16; ++e) v[e] = gelu_erf(v[e]);
    }
    if (OUT32) {
#pragma unroll
      for (int t = 0; t < 4; ++t) {
        float4 w4 = {v[t * 4 + 0], v[t * 4 + 1], v[t * 4 + 2], v[t * 4 + 3]};
        *(float4*)(out32 + gbase + t * 4) = w4;
      }
    }
    if (OUTB) {
#pragma unroll
      for (int t = 0; t < 2; ++t) {
        union { u16 q[8]; uint4 u; } pk;
#pragma unroll
        for (int j = 0; j < 8; ++j) pk.q[j] = f2b(v[t * 8 + j]);
        *(uint4*)(outb + gbase + t * 8) = pk.u;
      }
    }
  }
}

// ---------------- MFMA local windowed causal attention (window=64) ----------
__global__ __launch_bounds__(256) void local_attn_mfma(const u16* __restrict__ qkv,
                                                       u16* __restrict__ outb) {
  __shared__ u16 vt[64][152];      // V^T: [dim][key 0..143, pad->152]
  __shared__ u16 pb[4][16][104];   // per-wave P: [query][key 0..95 pad 104]
  const int tid = threadIdx.x;
  const int lane = tid & 63, w = tid >> 6;
  const int c = lane & 15, quad = lane >> 4;
  const int bx = blockIdx.x;
  const int qb = bx & 7, h = (bx >> 3) & 7, bb = bx >> 6;
  const int i0 = qb * 64;
  const int hc = h * 64;
  const size_t rbase = (size_t)bb * 512;

  {
    int r = tid >> 1;              // 0..127
    int d0 = (tid & 1) * 32;
    int key = i0 - 64 + r;
    if (key < 0) key = 0;
    if (key > 511) key = 511;
    const u16* Vr = qkv + (rbase + key) * 1536 + 1024 + hc + d0;
#pragma unroll
    for (int g = 0; g < 4; ++g) {
      union { u16 q[8]; uint4 u; } vv;
      vv.u = *(const uint4*)(Vr + g * 8);
#pragma unroll
      for (int j = 0; j < 8; ++j) vt[d0 + g * 8 + j][r] = vv.q[j];
    }
    if (tid < 128) {               // keys 128..143
      int r2 = 128 + (tid >> 3);
      int d2 = (tid & 7) * 8;
      int key2 = i0 - 64 + r2;
      if (key2 < 0) key2 = 0;
      if (key2 > 511) key2 = 511;
      const u16* Vr2 = qkv + (rbase + key2) * 1536 + 1024 + hc + d2;
      union { u16 q[8]; uint4 u; } vv2;
      vv2.u = *(const uint4*)Vr2;
#pragma unroll
      for (int j = 0; j < 8; ++j) vt[d2 + j][r2] = vv2.q[j];
    }
  }
  __syncthreads();

  const int i0w = i0 + 16 * w;
  const int kg0 = i0w - 64;

  bf16x8 qf0, qf1;
  {
    const u16* Qr = qkv + (rbase + i0w + c) * 1536 + hc + quad * 8;
    qf0 = *(const bf16x8*)Qr;
    qf1 = *(const bf16x8*)(Qr + 32);
  }

  f32x4 s[5];
#pragma unroll
  for (int kb = 0; kb < 5; ++kb) {
    int key = kg0 + kb * 16 + c; if (key < 0) key = 0;
    const u16* Kr = qkv + (rbase + key) * 1536 + 512 + hc + quad * 8;
    bf16x8 k0 = *(const bf16x8*)Kr;
    bf16x8 k1 = *(const bf16x8*)(Kr + 32);
    f32x4 z = {0.f, 0.f, 0.f, 0.f};
    z = __builtin_amdgcn_mfma_f32_16x16x32_bf16(qf0, k0, z, 0, 0, 0);
    s[kb] = __builtin_amdgcn_mfma_f32_16x16x32_bf16(qf1, k1, z, 0, 0, 0);
  }

  float mx[4];
#pragma unroll
  for (int r = 0; r < 4; ++r) {
    int row = quad * 4 + r;
    float m = -1e30f;
#pragma unroll
    for (int kb = 0; kb < 5; ++kb) {
      float v = s[kb][r] * 0.125f;
      int key = kg0 + kb * 16 + c;
      bool ok = key >= 0;
      if (kb == 0) ok = ok && (c >= row);
      if (kb == 4) ok = ok && (c <= row);
      v = ok ? v : -1e30f;
      s[kb][r] = v;
      m = fmaxf(m, v);
    }
    mx[r] = m;
  }
#pragma unroll
  for (int o = 1; o <= 8; o <<= 1)
#pragma unroll
    for (int r = 0; r < 4; ++r) mx[r] = fmaxf(mx[r], __shfl_xor(mx[r], o));

  float l[4] = {0.f, 0.f, 0.f, 0.f};
#pragma unroll
  for (int kb = 0; kb < 5; ++kb)
#pragma unroll
    for (int r = 0; r < 4; ++r) {
      u16 pq = f2b(__expf(s[kb][r] - mx[r]));
      l[r] += b2f(pq);
      pb[w][quad * 4 + r][kb * 16 + c] = pq;
    }
#pragma unroll
  for (int r = 0; r < 4; ++r) pb[w][quad * 4 + r][80 + c] = 0;
#pragma unroll
  for (int o = 1; o <= 8; o <<= 1)
#pragma unroll
    for (int r = 0; r < 4; ++r) l[r] += __shfl_xor(l[r], o);
  float inv[4];
#pragma unroll
  for (int r = 0; r < 4; ++r) inv[r] = 1.f / l[r];

  f32x4 o4[4];
#pragma unroll
  for (int nb = 0; nb < 4; ++nb) o4[nb] = f32x4{0.f, 0.f, 0.f, 0.f};
#pragma unroll
  for (int kt = 0; kt < 3; ++kt) {
    bf16x8 pa = *(const bf16x8*)&pb[w][c][kt * 32 + quad * 8];
#pragma unroll
    for (int nb = 0; nb < 4; ++nb) {
      bf16x8 vb = *(const bf16x8*)&vt[nb * 16 + c][16 * w + kt * 32 + quad * 8];
      o4[nb] = __builtin_amdgcn_mfma_f32_16x16x32_bf16(pa, vb, o4[nb], 0, 0, 0);
    }
  }
#pragma unroll
  for (int nb = 0; nb < 4; ++nb)
#pragma unroll
    for (int r = 0; r < 4; ++r) {
      int seq = i0w + quad * 4 + r;
      outb[(rbase + seq) * 512 + hc + nb * 16 + c] = f2b(o4[nb][r] * inv[r]);
    }
}

// ---------------- MFMA global attention over 32 anchors ---------------------
__global__ __launch_bounds__(256) void global_attn_mfma(const u16* __restrict__ qg,
                                                        const u16* __restrict__ kvg,
                                                        u16* __restrict__ outb) {
  __shared__ u16 vt[64][40];
  __shared__ u16 pb[4][16][40];
  const int tid = threadIdx.x;
  const int lane = tid & 63, w = tid >> 6;
  const int c = lane & 15, quad = lane >> 4;
  const int bx = blockIdx.x;
  const int qb = bx & 7, h = (bx >> 3) & 7, bb = bx >> 6;
  const int i0 = qb * 64;
  const int hc = h * 64;
  const size_t rbase = (size_t)bb * 512;

  {
    int r = tid >> 3;
    int d0 = (tid & 7) * 8;
    const u16* Vr = kvg + ((size_t)bb * 32 + r) * 1024 + 512 + hc + d0;
    union { u16 q[8]; uint4 u; } vv;
    vv.u = *(const uint4*)Vr;
#pragma unroll
    for (int j = 0; j < 8; ++j) vt[d0 + j][r] = vv.q[j];
  }
  __syncthreads();

  const int i0w = i0 + 16 * w;
  bf16x8 qf0, qf1;
  {
    const u16* Qr = qg + (rbase + i0w + c) * 512 + hc + quad * 8;
    qf0 = *(const bf16x8*)Qr;
    qf1 = *(const bf16x8*)(Qr + 32);
  }
  f32x4 s[2];
#pragma unroll
  for (int kb = 0; kb < 2; ++kb) {
    const u16* Kr = kvg + ((size_t)bb * 32 + kb * 16 + c) * 1024 + hc + quad * 8;
    bf16x8 k0 = *(const bf16x8*)Kr;
    bf16x8 k1 = *(const bf16x8*)(Kr + 32);
    f32x4 z = {0.f, 0.f, 0.f, 0.f};
    z = __builtin_amdgcn_mfma_f32_16x16x32_bf16(qf0, k0, z, 0, 0, 0);
    s[kb] = __builtin_amdgcn_mfma_f32_16x16x32_bf16(qf1, k1, z, 0, 0, 0);
  }
  float mx[4];
#pragma unroll
  for (int r = 0; r < 4; ++r)
    mx[r] = fmaxf(s[0][r] * 0.125f, s[1][r] * 0.125f);
#pragma unroll
  for (int o = 1; o <= 8; o <<= 1)
#pragma unroll
    for (int r = 0; r < 4; ++r) mx[r] = fmaxf(mx[r], __shfl_xor(mx[r], o));
  float l[4] = {0.f, 0.f, 0.f, 0.f};
#pragma unroll
  for (int kb = 0; kb < 2; ++kb)
#pragma unroll
    for (int r = 0; r < 4; ++r) {
      u16 pq = f2b(__expf(s[kb][r] * 0.125f - mx[r]));
      l[r] += b2f(pq);
      pb[w][quad * 4 + r][kb * 16 + c] = pq;
    }
#pragma unroll
  for (int o = 1; o <= 8; o <<= 1)
#pragma unroll
    for (int r = 0; r < 4; ++r) l[r] += __shfl_xor(l[r], o);
  float inv[4];
#pragma unroll
  for (int r = 0; r < 4; ++r) inv[r] = 1.f / l[r];

  f32x4 o4[4];
#pragma unroll
  for (int nb = 0; nb < 4; ++nb) o4[nb] = f32x4{0.f, 0.f, 0.f, 0.f};
  bf16x8 pa = *(const bf16x8*)&pb[w][c][quad * 8];
#pragma unroll
  for (int nb = 0; nb < 4; ++nb) {
    bf16x8 vb = *(const bf16x8*)&vt[nb * 16 + c][quad * 8];
    o4[nb] = __builtin_amdgcn_mfma_f32_16x16x32_bf16(pa, vb, o4[nb], 0, 0, 0);
  }
#pragma unroll
  for (int nb = 0; nb < 4; ++nb)
#pragma unroll
    for (int r = 0; r < 4; ++r) {
      int seq = i0w + quad * 4 + r;
      outb[(rbase + seq) * 512 + hc + nb * 16 + c] = f2b(o4[nb][r] * inv[r]);
    }
}

// ---------------- LayerNorm over 512 cols, one wave per row -----------------
__global__ __launch_bounds__(256) void ln_b2b(const u16* __restrict__ in,
                                              const float* __restrict__ gg,
                                              const float* __restrict__ bb,
                                              u16* __restrict__ outb) {
  const int lane = threadIdx.x & 63;
  const size_t row = (size_t)blockIdx.x * 4 + (threadIdx.x >> 6);
  union { u16 q[8]; uint4 u; } pk;
  pk.u = *(const uint4*)(in + row * 512 + lane * 8);
  float v[8];
#pragma unroll
  for (int e = 0; e < 8; ++e) v[e] = b2f(pk.q[e]);
  float sm = 0.f, sq = 0.f;
#pragma unroll
  for (int e = 0; e < 8; ++e) { sm += v[e]; sq += v[e] * v[e]; }
#pragma unroll
  for (int o = 32; o; o >>= 1) { sm += __shfl_xor(sm, o); sq += __shfl_xor(sq, o); }
  float mean = sm * (1.0f / 512.0f);
  float var = sq * (1.0f / 512.0f) - mean * mean;
  float rs = rsqrtf(var + 1e-5f);
  float4 ga = *(const float4*)(gg + lane * 8);
  float4 gb = *(const float4*)(gg + lane * 8 + 4);
  float4 ba = *(const float4*)(bb + lane * 8);
  float4 bbv = *(const float4*)(bb + lane * 8 + 4);
  float gv[8] = {ga.x, ga.y, ga.z, ga.w, gb.x, gb.y, gb.z, gb.w};
  float bv[8] = {ba.x, ba.y, ba.z, ba.w, bbv.x, bbv.y, bbv.z, bbv.w};
  union { u16 q[8]; uint4 u; } po;
#pragma unroll
  for (int e = 0; e < 8; ++e) po.q[e] = f2b((v[e] - mean) * rs * gv[e] + bv[e]);
  *(uint4*)(outb + row * 512 + lane * 8) = po.u;
}

__global__ __launch_bounds__(256) void ln_f2f(const float* __restrict__ in,
                                              const float* __restrict__ gg,
                                              const float* __restrict__ bb,
                                              float* __restrict__ out) {
  const int lane = threadIdx.x & 63;
  const size_t row = (size_t)blockIdx.x * 4 + (threadIdx.x >> 6);
  const float* p = in + row * 512 + lane * 8;
  float4 a = *(const float4*)p;
  float4 b = *(const float4*)(p + 4);
  float v[8] = {a.x, a.y, a.z, a.w, b.x, b.y, b.z, b.w};
  float sm = 0.f, sq = 0.f;
#pragma unroll
  for (int e = 0; e < 8; ++e) { sm += v[e]; sq += v[e] * v[e]; }
#pragma unroll
  for (int o = 32; o; o >>= 1) { sm += __shfl_xor(sm, o); sq += __shfl_xor(sq, o); }
  float mean = sm * (1.0f / 512.0f);
  float var = sq * (1.0f / 512.0f) - mean * mean;
  float rs = rsqrtf(var + 1e-5f);
  float4 ga = *(const float4*)(gg + lane * 8);
  float4 gb = *(const float4*)(gg + lane * 8 + 4);
  float4 ba = *(const float4*)(bb + lane * 8);
  float4 bbv = *(const float4*)(bb + lane * 8 + 4);
  float gv[8] = {ga.x, ga.y, ga.z, ga.w, gb.x, gb.y, gb.z, gb.w};
  float bv[8] = {ba.x, ba.y, ba.z, ba.w, bbv.x, bbv.y, bbv.z, bbv.w};
  float r[8];
#pragma unroll
  for (int e = 0; e < 8; ++e) r[e] = (v[e] - mean) * rs * gv[e] + bv[e];
  float4 r1 = {r[0], r[1], r[2], r[3]};
  float4 r2 = {r[4], r[5], r[6], r[7]};
  *(float4*)(out + row * 512 + lane * 8) = r1;
  *(float4*)(out + row * 512 + lane * 8 + 4) = r2;
}

// ---------------- driver -----------------------------------------------------
extern "C" void kernel_launch(void* const* d_in, const int* in_sizes, int n_in,
                              void* d_out, int out_size, void* d_ws, size_t ws_size,
                              hipStream_t stream) {
  const float* x      = (const float*)d_in[0];
  const float* anchors= (const float*)d_in[1];
  const float* lw_in  = (const float*)d_in[2];
  const float* lb_in  = (const float*)d_in[3];
  const float* lw_out = (const float*)d_in[4];
  const float* lb_out = (const float*)d_in[5];
  const float* gw_in  = (const float*)d_in[6];
  const float* gb_in  = (const float*)d_in[7];
  const float* gw_out = (const float*)d_in[8];
  const float* gb_out = (const float*)d_in[9];
  const float* w1     = (const float*)d_in[10];
  const float* b1     = (const float*)d_in[11];
  const float* w2     = (const float*)d_in[12];
  const float* b2     = (const float*)d_in[13];
  const float* g1     = (const float*)d_in[14];
  const float* be1    = (const float*)d_in[15];
  const float* g2     = (const float*)d_in[16];
  const float* be2    = (const float*)d_in[17];
  (void)in_sizes; (void)n_in; (void)out_size;
  float* out = (float*)d_out;

  char* ws = (char*)d_ws;
  size_t o = 0;
  auto nxt = [&](size_t bytes) { char* p = ws + o; o += bytes; return p; };
  u16* lwib = (u16*)nxt((size_t)1536 * 512 * 2);
  u16* lwob = (u16*)nxt((size_t)512 * 512 * 2);
  u16* gwib = (u16*)nxt((size_t)1536 * 512 * 2);
  u16* gwob = (u16*)nxt((size_t)512 * 512 * 2);
  u16* w1b  = (u16*)nxt((size_t)2048 * 512 * 2);
  u16* w2b  = (u16*)nxt((size_t)512 * 2048 * 2);
  u16* ab   = (u16*)nxt((size_t)2048 * 512 * 2);
  u16* kvgb = (u16*)nxt((size_t)2048 * 1024 * 2);
  const size_t wbytes = o;

  int nc = 1;
  while (wbytes + (size_t)(32768 / nc) * 6144 > ws_size && nc < 32) nc <<= 1;
  const int Mc = 32768 / nc;
  const int nBat = Mc / 512;
  const int mb = Mc >> 8;   // 256-row tiles
  u16* BIGb = (u16*)nxt((size_t)Mc * 4096);
  u16* Pb   = (u16*)nxt((size_t)Mc * 1024);
  u16* Qb   = (u16*)nxt((size_t)Mc * 1024);
  u16* Sb   = BIGb + (size_t)Mc * 1536;

  conv1<<<384, 256, 0, stream>>>(lw_in, lwib);
  conv1<<<128, 256, 0, stream>>>(lw_out, lwob);
  conv1<<<384, 256, 0, stream>>>(gw_in, gwib);
  conv1<<<128, 256, 0, stream>>>(gw_out, gwob);
  conv1<<<512, 256, 0, stream>>>(w1, w1b);
  conv1<<<512, 256, 0, stream>>>(w2, w2b);
  conv1<<<512, 256, 0, stream>>>(anchors, ab);
  gemm256<false, false, false, false, true><<<8 * 4, 512, 0, stream>>>(
      ab, gwib + 512 * 512, gb_in + 512, nullptr, nullptr, nullptr, kvgb, 2048, 1024, 512);

  for (int ck = 0; ck < nc; ++ck) {
    const size_t r0 = (size_t)ck * Mc;
    const float* xck = x + r0 * 512;
    conv1<<<Mc / 4, 256, 0, stream>>>(xck, Pb);
    gemm256<false, false, false, false, true><<<mb * 6, 512, 0, stream>>>(
        Pb, lwib, lb_in, nullptr, nullptr, nullptr, BIGb, Mc, 1536, 512);
    local_attn_mfma<<<nBat * 64, 256, 0, stream>>>(BIGb, Sb);
    gemm256<false, true, false, false, true><<<mb * 2, 512, 0, stream>>>(
        Sb, lwob, lb_out, xck, nullptr, nullptr, Qb, Mc, 512, 512);
    gemm256<false, false, false, false, true><<<mb * 2, 512, 0, stream>>>(
        Qb, gwib, gb_in, nullptr, nullptr, nullptr, Pb, Mc, 512, 512);
    global_attn_mfma<<<nBat * 64, 256, 0, stream>>>(Pb, kvgb + (r0 / 512) * 32 * 1024, Sb);
    gemm256<false, false, true, false, true><<<mb * 2, 512, 0, stream>>>(
        Sb, gwob, gb_out, nullptr, Qb, nullptr, Pb, Mc, 512, 512);
    ln_b2b<<<Mc / 4, 256, 0, stream>>>(Pb, g1, be1, Qb);
    gemm256<true, false, false, false, true><<<mb * 8, 512, 0, stream>>>(
        Qb, w1b, b1, nullptr, nullptr, nullptr, BIGb, Mc, 2048, 512);
    gemm256<false, false, true, true, false><<<mb * 2, 512, 0, stream>>>(
        BIGb, w2b, b2, nullptr, Qb, out + r0 * 512, nullptr, Mc, 512, 2048);
    ln_f2f<<<Mc / 4, 256, 0, stream>>>(out + r0 * 512, g2, be2, out + r0 * 512);
  }
}